// Round 4
// baseline (235.617 us; speedup 1.0000x reference)
//
#include <hip/hip_runtime.h>
#include <hip/hip_bf16.h>

typedef __attribute__((ext_vector_type(8))) short bf16x8;
typedef __attribute__((ext_vector_type(4))) float f32x4;

static __device__ __forceinline__ unsigned short f2bf(float f) {
    unsigned u = __builtin_bit_cast(unsigned, f);
    unsigned rounding = 0x7fffu + ((u >> 16) & 1u);
    u += rounding;
    return (unsigned short)(u >> 16);
}

static __device__ __forceinline__ void async_copy16(const void* g, void* l) {
    __builtin_amdgcn_global_load_lds(
        (const __attribute__((address_space(1))) unsigned int*)g,
        (__attribute__((address_space(3))) unsigned int*)l,
        16, 0, 0);
}

#define BARRIER() __builtin_amdgcn_s_barrier()
#define LGKM0()  do { asm volatile("s_waitcnt lgkmcnt(0)" ::: "memory"); \
                      __builtin_amdgcn_sched_barrier(0); } while (0)

// fast erf-gelu via tanh approximation (|err| <= ~3e-3, threshold margin 0.07+)
static __device__ __forceinline__ float fast_gelu(float y) {
    float u = 0.7978845608028654f * y * (1.0f + 0.044715f * y * y);
    float au = fminf(fabsf(u), 9.0f);
    float e = __expf(-2.0f * au);
    float th = (1.0f - e) * __builtin_amdgcn_rcpf(1.0f + e);
    th = (u < 0.0f) ? -th : th;
    return 0.5f * y * (1.0f + th);
}

// ---------------- LayerNorm (fp32) -> bf16 cast ----------------
__global__ __launch_bounds__(256) void ln_cast_kernel(
    const float* __restrict__ x, const float* __restrict__ gamma,
    const float* __restrict__ beta, unsigned short* __restrict__ out) {
    const int row = blockIdx.x;
    const int t = threadIdx.x;
    const float4 v = ((const float4*)(x + (size_t)row * 1024))[t];

    float s  = v.x + v.y + v.z + v.w;
    float ss = v.x * v.x + v.y * v.y + v.z * v.z + v.w * v.w;
    #pragma unroll
    for (int off = 32; off; off >>= 1) {
        s  += __shfl_down(s, off);
        ss += __shfl_down(ss, off);
    }
    __shared__ float red[8];
    const int wid = t >> 6, lane = t & 63;
    if (lane == 0) { red[wid] = s; red[wid + 4] = ss; }
    __syncthreads();
    if (t == 0) {
        float S  = red[0] + red[1] + red[2] + red[3];
        float SS = red[4] + red[5] + red[6] + red[7];
        float mu = S * (1.0f / 1024.0f);
        float var = SS * (1.0f / 1024.0f) - mu * mu;
        red[0] = mu;
        red[1] = rsqrtf(var + 1e-7f);
    }
    __syncthreads();
    const float mu = red[0], rs = red[1];
    const float4 g = ((const float4*)gamma)[t];
    const float4 b = ((const float4*)beta)[t];

    ushort4 pk;
    pk.x = f2bf((v.x - mu) * rs * g.x + b.x);
    pk.y = f2bf((v.y - mu) * rs * g.y + b.y);
    pk.z = f2bf((v.z - mu) * rs * g.z + b.z);
    pk.w = f2bf((v.w - mu) * rs * g.w + b.w);
    ((ushort4*)(out + (size_t)row * 1024))[t] = pk;
}

// ---------------- W [1024][4096] fp32 -> Wt [4096][1024] bf16 ----------------
__global__ __launch_bounds__(256) void wt_cast_kernel(
    const float* __restrict__ W, unsigned short* __restrict__ Wt) {
    __shared__ float tile[32][33];
    const int bx = blockIdx.x;
    const int by = blockIdx.y;
    const int tx = threadIdx.x & 31;
    const int ty = threadIdx.x >> 5;
    #pragma unroll
    for (int i = 0; i < 4; ++i) {
        int k = by * 32 + ty + i * 8;
        tile[ty + i * 8][tx] = W[(size_t)k * 4096 + bx * 32 + tx];
    }
    __syncthreads();
    #pragma unroll
    for (int i = 0; i < 4; ++i) {
        int n = bx * 32 + ty + i * 8;
        Wt[(size_t)n * 1024 + by * 32 + tx] = f2bf(tile[tx][ty + i * 8]);
    }
}

// ---------------- GEMM 128x128 tile, BK=32, TRIPLE-buffered LDS (48KB, 3 blocks/CU)
// Counted-vmcnt pipeline: stage kt+2 -> read+MFMA kt -> vmcnt(4) -> barrier.
// LDS layout per buf: A[128 rows][32k] 8KB + B 8KB, 64B rows, chunk swizzle
// c ^= (row>>1)&3 -> wave ds_read_b128 covers one contiguous 1KB region
// (conflict-free); gload_lds writes 64 consecutive slots (conflict-free).
__global__ __launch_bounds__(256, 3) void gemm_kernel(
    const unsigned short* __restrict__ A, const unsigned short* __restrict__ Wt,
    const float* __restrict__ bias, float* __restrict__ out) {
    __shared__ char lds_mem[49152];   // 3 bufs x (A 8KB | B 8KB)

    const int bid = blockIdx.x;                 // 4096 blocks, %8==0 -> bijective
    const int swz = (bid & 7) * 512 + (bid >> 3);
    const int bm = swz >> 5;                    // 0..127
    const int bn = swz & 31;                    // 0..31

    const int t = threadIdx.x;
    const int lane = t & 63;
    const int wid = t >> 6;
    const int wm = wid >> 1, wn = wid & 1;
    const int lrow = lane & 15;
    const int lk = lane >> 4;                   // 0..3

    // staging: thread t owns slots {t, t+256} of A and of B.
    // slot s: row = s>>2 (64B rows), lds chunk = s&3, global chunk = (s&3)^((s>>3)&3)
    const int srow = t >> 2;                    // 0..63 (second slot: +64)
    const int sc = (t & 3) ^ ((t >> 3) & 3);
    const unsigned short* gA0 = A  + (size_t)(bm * 128 + srow) * 1024 + sc * 8;
    const unsigned short* gB0 = Wt + (size_t)(bn * 128 + srow) * 1024 + sc * 8;
    const int lslot = t * 16;                   // lane*16 within wave + wave*1024

    auto stage = [&](int kt, char* buf) {
        async_copy16(gA0 + kt * 32,                    buf + lslot);
        async_copy16(gA0 + (size_t)64 * 1024 + kt * 32, buf + 4096 + lslot);
        async_copy16(gB0 + kt * 32,                    buf + 8192 + lslot);
        async_copy16(gB0 + (size_t)64 * 1024 + kt * 32, buf + 12288 + lslot);
    };

    // read side: frag row R = (wm|wn)*64 + mi*16 + lrow, k-chunk lk
    // swizzled chunk uses (R>>1)&3 == (lrow>>1)&3 (mi*16, w*64 are 0 mod 8)
    const int swzc = (lk ^ ((lrow >> 1) & 3)) * 16;
    const int aOff = (wm * 64 + lrow) * 64 + swzc;          // + mi*16*64
    const int bOff = 8192 + (wn * 64 + lrow) * 64 + swzc;   // + ni*16*64

    f32x4 acc[4][4];
    #pragma unroll
    for (int i = 0; i < 4; ++i)
        #pragma unroll
        for (int j = 0; j < 4; ++j) acc[i][j] = (f32x4)0.0f;

    // prologue: stage kt=0 -> buf0, kt=1 -> buf1; wait buf0 (own 4 oldest)
    stage(0, lds_mem);
    stage(1, lds_mem + 16384);
    asm volatile("s_waitcnt vmcnt(4)" ::: "memory");
    __builtin_amdgcn_sched_barrier(0);
    BARRIER();

    const int NKT = 32;
    int cb = 0;  // kt % 3
    for (int kt = 0; kt < NKT; ++kt) {
        char* cbuf = lds_mem + cb * 16384;
        if (kt + 2 < NKT) {
            char* sbuf = lds_mem + ((cb >= 1) ? (cb - 1) : 2) * 16384;  // (kt+2)%3
            stage(kt + 2, sbuf);
        }

        bf16x8 af[4], bf[4];
        #pragma unroll
        for (int mi = 0; mi < 4; ++mi)
            af[mi] = *(const bf16x8*)(cbuf + aOff + mi * 16 * 64);
        #pragma unroll
        for (int ni = 0; ni < 4; ++ni)
            bf[ni] = *(const bf16x8*)(cbuf + bOff + ni * 16 * 64);
        LGKM0();
        __builtin_amdgcn_s_setprio(1);
        #pragma unroll
        for (int mi = 0; mi < 4; ++mi)
            #pragma unroll
            for (int ni = 0; ni < 4; ++ni)
                acc[mi][ni] = __builtin_amdgcn_mfma_f32_16x16x32_bf16(
                    af[mi], bf[ni], acc[mi][ni], 0, 0, 0);
        __builtin_amdgcn_s_setprio(0);

        if (kt <= NKT - 3) {
            asm volatile("s_waitcnt vmcnt(4)" ::: "memory");   // kt+1's stages landed
            __builtin_amdgcn_sched_barrier(0);
            BARRIER();
        } else if (kt == NKT - 2) {
            asm volatile("s_waitcnt vmcnt(0)" ::: "memory");   // last buf landed
            __builtin_amdgcn_sched_barrier(0);
            BARRIER();
        }
        cb = (cb == 2) ? 0 : cb + 1;
    }

    // ---- epilogue: bias + fast gelu, fp32 store
    float bv[4];
    #pragma unroll
    for (int ni = 0; ni < 4; ++ni) bv[ni] = bias[bn * 128 + wn * 64 + ni * 16 + lrow];
    #pragma unroll
    for (int mi = 0; mi < 4; ++mi) {
        const int row0 = bm * 128 + wm * 64 + mi * 16 + lk * 4;
        #pragma unroll
        for (int ni = 0; ni < 4; ++ni) {
            const int col = bn * 128 + wn * 64 + ni * 16 + lrow;
            #pragma unroll
            for (int r = 0; r < 4; ++r) {
                float y = acc[mi][ni][r] + bv[ni];
                out[(size_t)(row0 + r) * 4096 + col] = fast_gelu(y);
            }
        }
    }
}

extern "C" void kernel_launch(void* const* d_in, const int* in_sizes, int n_in,
                              void* d_out, int out_size, void* d_ws, size_t ws_size,
                              hipStream_t stream) {
    const float* hidden = (const float*)d_in[0];
    const float* gamma  = (const float*)d_in[1];
    const float* beta   = (const float*)d_in[2];
    const float* W      = (const float*)d_in[3];
    const float* bias   = (const float*)d_in[4];
    float* out = (float*)d_out;

    unsigned short* Abf = (unsigned short*)d_ws;
    unsigned short* Wt  = (unsigned short*)((char*)d_ws + (size_t)16384 * 1024 * 2);

    ln_cast_kernel<<<16384, 256, 0, stream>>>(hidden, gamma, beta, Abf);
    wt_cast_kernel<<<dim3(128, 32), 256, 0, stream>>>(W, Wt);
    gemm_kernel<<<4096, 256, 0, stream>>>(Abf, Wt, bias, out);
}

// Round 5
// 227.584 us; speedup vs baseline: 1.0353x; 1.0353x over previous
//
#include <hip/hip_runtime.h>
#include <hip/hip_bf16.h>

typedef __attribute__((ext_vector_type(8))) short bf16x8;
typedef __attribute__((ext_vector_type(16))) float f32x16;

static __device__ __forceinline__ unsigned short f2bf(float f) {
    unsigned u = __builtin_bit_cast(unsigned, f);
    unsigned rounding = 0x7fffu + ((u >> 16) & 1u);
    u += rounding;
    return (unsigned short)(u >> 16);
}

static __device__ __forceinline__ void async_copy16(const void* g, void* l) {
    __builtin_amdgcn_global_load_lds(
        (const __attribute__((address_space(1))) unsigned int*)g,
        (__attribute__((address_space(3))) unsigned int*)l,
        16, 0, 0);
}

#define BARRIER() __builtin_amdgcn_s_barrier()
#define VM0()    do { asm volatile("s_waitcnt vmcnt(0)" ::: "memory"); \
                      __builtin_amdgcn_sched_barrier(0); } while (0)

// fast erf-gelu via tanh approximation (|err| <= ~3e-3, threshold margin 0.07+)
static __device__ __forceinline__ float fast_gelu(float y) {
    float u = 0.7978845608028654f * y * (1.0f + 0.044715f * y * y);
    float au = fminf(fabsf(u), 9.0f);
    float e = __expf(-2.0f * au);
    float th = (1.0f - e) * __builtin_amdgcn_rcpf(1.0f + e);
    th = (u < 0.0f) ? -th : th;
    return 0.5f * y * (1.0f + th);
}

// ---------------- LayerNorm (fp32) -> bf16 cast ----------------
__global__ __launch_bounds__(256) void ln_cast_kernel(
    const float* __restrict__ x, const float* __restrict__ gamma,
    const float* __restrict__ beta, unsigned short* __restrict__ out) {
    const int row = blockIdx.x;
    const int t = threadIdx.x;
    const float4 v = ((const float4*)(x + (size_t)row * 1024))[t];

    float s  = v.x + v.y + v.z + v.w;
    float ss = v.x * v.x + v.y * v.y + v.z * v.z + v.w * v.w;
    #pragma unroll
    for (int off = 32; off; off >>= 1) {
        s  += __shfl_down(s, off);
        ss += __shfl_down(ss, off);
    }
    __shared__ float red[8];
    const int wid = t >> 6, lane = t & 63;
    if (lane == 0) { red[wid] = s; red[wid + 4] = ss; }
    __syncthreads();
    if (t == 0) {
        float S  = red[0] + red[1] + red[2] + red[3];
        float SS = red[4] + red[5] + red[6] + red[7];
        float mu = S * (1.0f / 1024.0f);
        float var = SS * (1.0f / 1024.0f) - mu * mu;
        red[0] = mu;
        red[1] = rsqrtf(var + 1e-7f);
    }
    __syncthreads();
    const float mu = red[0], rs = red[1];
    const float4 g = ((const float4*)gamma)[t];
    const float4 b = ((const float4*)beta)[t];

    ushort4 pk;
    pk.x = f2bf((v.x - mu) * rs * g.x + b.x);
    pk.y = f2bf((v.y - mu) * rs * g.y + b.y);
    pk.z = f2bf((v.z - mu) * rs * g.z + b.z);
    pk.w = f2bf((v.w - mu) * rs * g.w + b.w);
    ((ushort4*)(out + (size_t)row * 1024))[t] = pk;
}

// ---------------- W [1024][4096] fp32 -> Wt [4096][1024] bf16 ----------------
__global__ __launch_bounds__(256) void wt_cast_kernel(
    const float* __restrict__ W, unsigned short* __restrict__ Wt) {
    __shared__ float tile[32][33];
    const int bx = blockIdx.x;
    const int by = blockIdx.y;
    const int tx = threadIdx.x & 31;
    const int ty = threadIdx.x >> 5;
    #pragma unroll
    for (int i = 0; i < 4; ++i) {
        int k = by * 32 + ty + i * 8;
        tile[ty + i * 8][tx] = W[(size_t)k * 4096 + bx * 32 + tx];
    }
    __syncthreads();
    #pragma unroll
    for (int i = 0; i < 4; ++i) {
        int n = bx * 32 + ty + i * 8;
        Wt[(size_t)n * 1024 + by * 32 + tx] = f2bf(tile[tx][ty + i * 8]);
    }
}

// ---------------- GEMM 128x128 tile, BK=64, dbuf LDS 64KB, 2 blocks/CU ----------------
// R3 skeleton; 32x32x16 MFMA (2x2 frags per 64x64 wave tile); compiler-scheduled
// lgkmcnt interleave (no explicit LDS drain).
__global__ __launch_bounds__(256, 2) void gemm_kernel(
    const unsigned short* __restrict__ A, const unsigned short* __restrict__ Wt,
    const float* __restrict__ bias, float* __restrict__ out) {
    __shared__ char lds_mem[65536];   // [2 bufs][A 16KB | B 16KB]

    const int bid = blockIdx.x;                 // 4096 blocks, %8==0 -> bijective
    const int swz = (bid & 7) * 512 + (bid >> 3);
    const int bm = swz >> 5;                    // 0..127
    const int bn = swz & 31;                    // 0..31

    const int t = threadIdx.x;
    const int lane = t & 63;
    const int wid = t >> 6;
    const int wm = wid >> 1, wn = wid & 1;
    const int l31 = lane & 31;
    const int hi = lane >> 5;                   // 0/1
    const int rsw = lane & 7;                   // row&7 for all frag rows

    // staging: thread t -> row (t>>3)+32*i, 16B chunk (t&7); src pre-swizzled
    const int srr = t >> 3;                     // 0..31
    const int sch = t & 7;
    const int sgc = sch ^ (srr & 7);
    const unsigned short* gA = A  + (size_t)(bm * 128 + srr) * 1024 + sgc * 8;
    const unsigned short* gB = Wt + (size_t)(bn * 128 + srr) * 1024 + sgc * 8;
    const int lst = srr * 128 + sch * 16;

    auto stage = [&](int kt, char* buf) {
        #pragma unroll
        for (int i = 0; i < 4; ++i) {
            async_copy16(gA + (size_t)(i * 32) * 1024 + kt * 64, buf + i * 32 * 128 + lst);
            async_copy16(gB + (size_t)(i * 32) * 1024 + kt * 64, buf + 16384 + i * 32 * 128 + lst);
        }
    };

    // read side: frag row R = w*64 + f*32 + l31 (R&7 == lane&7); k-slice s (0..3):
    // chunk c = 2s + hi, LDS slot = c ^ (R&7). addr = R*128 + slot*16.
    const int aRow = (wm * 64 + l31) * 128;             // + f*32*128
    const int bRow = 16384 + (wn * 64 + l31) * 128;     // + f*32*128
    int cks[4];
    #pragma unroll
    for (int s = 0; s < 4; ++s) cks[s] = ((2 * s + hi) ^ rsw) * 16;

    f32x16 acc[2][2];
    #pragma unroll
    for (int i = 0; i < 2; ++i)
        #pragma unroll
        for (int j = 0; j < 2; ++j) acc[i][j] = (f32x16)0.0f;

    // prologue
    stage(0, lds_mem);
    VM0();
    BARRIER();

    const int NKT = 16;
    for (int kt = 0; kt < NKT; ++kt) {
        char* cbuf = lds_mem + ((kt & 1) << 15);
        char* nbuf = lds_mem + (((kt + 1) & 1) << 15);

        if (kt + 1 < NKT) stage(kt + 1, nbuf);   // issue next-tile loads FIRST

        bf16x8 af[2][4], bf[2][4];
        #pragma unroll
        for (int s = 0; s < 4; ++s) {
            af[0][s] = *(const bf16x8*)(cbuf + aRow + cks[s]);
            af[1][s] = *(const bf16x8*)(cbuf + aRow + 32 * 128 + cks[s]);
            bf[0][s] = *(const bf16x8*)(cbuf + bRow + cks[s]);
            bf[1][s] = *(const bf16x8*)(cbuf + bRow + 32 * 128 + cks[s]);
        }
        // compiler inserts counted lgkmcnt between reads and MFMAs
        #pragma unroll
        for (int s = 0; s < 4; ++s)
            #pragma unroll
            for (int mi = 0; mi < 2; ++mi)
                #pragma unroll
                for (int ni = 0; ni < 2; ++ni)
                    acc[mi][ni] = __builtin_amdgcn_mfma_f32_32x32x16_bf16(
                        af[mi][s], bf[ni][s], acc[mi][ni], 0, 0, 0);

        VM0();       // next-tile gload_lds landed (hidden under reads+MFMA)
        BARRIER();   // all waves done with cbuf -> safe to restage next iter
    }

    // ---- epilogue: bias + fast gelu, fp32 store
    // C/D 32x32 layout: col = lane&31, row = (reg&3) + 8*(reg>>2) + 4*hi
    float bv[2];
    #pragma unroll
    for (int ni = 0; ni < 2; ++ni) bv[ni] = bias[bn * 128 + wn * 64 + ni * 32 + l31];
    #pragma unroll
    for (int mi = 0; mi < 2; ++mi)
        #pragma unroll
        for (int ni = 0; ni < 2; ++ni) {
            const int col = bn * 128 + wn * 64 + ni * 32 + l31;
            #pragma unroll
            for (int g = 0; g < 4; ++g) {
                const int row0 = bm * 128 + wm * 64 + mi * 32 + 8 * g + 4 * hi;
                #pragma unroll
                for (int r = 0; r < 4; ++r) {
                    float y = acc[mi][ni][g * 4 + r] + bv[ni];
                    out[(size_t)(row0 + r) * 4096 + col] = fast_gelu(y);
                }
            }
        }
}

extern "C" void kernel_launch(void* const* d_in, const int* in_sizes, int n_in,
                              void* d_out, int out_size, void* d_ws, size_t ws_size,
                              hipStream_t stream) {
    const float* hidden = (const float*)d_in[0];
    const float* gamma  = (const float*)d_in[1];
    const float* beta   = (const float*)d_in[2];
    const float* W      = (const float*)d_in[3];
    const float* bias   = (const float*)d_in[4];
    float* out = (float*)d_out;

    unsigned short* Abf = (unsigned short*)d_ws;
    unsigned short* Wt  = (unsigned short*)((char*)d_ws + (size_t)16384 * 1024 * 2);

    ln_cast_kernel<<<16384, 256, 0, stream>>>(hidden, gamma, beta, Abf);
    wt_cast_kernel<<<dim3(128, 32), 256, 0, stream>>>(W, Wt);
    gemm_kernel<<<4096, 256, 0, stream>>>(Abf, Wt, bias, out);
}

// Round 6
// 214.718 us; speedup vs baseline: 1.0973x; 1.0599x over previous
//
#include <hip/hip_runtime.h>
#include <hip/hip_bf16.h>

typedef __attribute__((ext_vector_type(8))) short bf16x8;
typedef __attribute__((ext_vector_type(4))) float f32x4;

static __device__ __forceinline__ unsigned short f2bf(float f) {
    unsigned u = __builtin_bit_cast(unsigned, f);
    unsigned rounding = 0x7fffu + ((u >> 16) & 1u);
    u += rounding;
    return (unsigned short)(u >> 16);
}

static __device__ __forceinline__ void async_copy16(const void* g, void* l) {
    __builtin_amdgcn_global_load_lds(
        (const __attribute__((address_space(1))) unsigned int*)g,
        (__attribute__((address_space(3))) unsigned int*)l,
        16, 0, 0);
}

#define BARRIER() __builtin_amdgcn_s_barrier()
#define VM0()    do { asm volatile("s_waitcnt vmcnt(0)" ::: "memory"); \
                      __builtin_amdgcn_sched_barrier(0); } while (0)

// fast erf-gelu via tanh approximation (|err| <= ~3e-3, threshold margin 0.07+)
static __device__ __forceinline__ float fast_gelu(float y) {
    float u = 0.7978845608028654f * y * (1.0f + 0.044715f * y * y);
    float au = fminf(fabsf(u), 9.0f);
    float e = __expf(-2.0f * au);
    float th = (1.0f - e) * __builtin_amdgcn_rcpf(1.0f + e);
    th = (u < 0.0f) ? -th : th;
    return 0.5f * y * (1.0f + th);
}

// ---------------- LayerNorm (fp32) -> bf16 cast ----------------
__global__ __launch_bounds__(256) void ln_cast_kernel(
    const float* __restrict__ x, const float* __restrict__ gamma,
    const float* __restrict__ beta, unsigned short* __restrict__ out) {
    const int row = blockIdx.x;
    const int t = threadIdx.x;
    const float4 v = ((const float4*)(x + (size_t)row * 1024))[t];

    float s  = v.x + v.y + v.z + v.w;
    float ss = v.x * v.x + v.y * v.y + v.z * v.z + v.w * v.w;
    #pragma unroll
    for (int off = 32; off; off >>= 1) {
        s  += __shfl_down(s, off);
        ss += __shfl_down(ss, off);
    }
    __shared__ float red[8];
    const int wid = t >> 6, lane = t & 63;
    if (lane == 0) { red[wid] = s; red[wid + 4] = ss; }
    __syncthreads();
    if (t == 0) {
        float S  = red[0] + red[1] + red[2] + red[3];
        float SS = red[4] + red[5] + red[6] + red[7];
        float mu = S * (1.0f / 1024.0f);
        float var = SS * (1.0f / 1024.0f) - mu * mu;
        red[0] = mu;
        red[1] = rsqrtf(var + 1e-7f);
    }
    __syncthreads();
    const float mu = red[0], rs = red[1];
    const float4 g = ((const float4*)gamma)[t];
    const float4 b = ((const float4*)beta)[t];

    ushort4 pk;
    pk.x = f2bf((v.x - mu) * rs * g.x + b.x);
    pk.y = f2bf((v.y - mu) * rs * g.y + b.y);
    pk.z = f2bf((v.z - mu) * rs * g.z + b.z);
    pk.w = f2bf((v.w - mu) * rs * g.w + b.w);
    ((ushort4*)(out + (size_t)row * 1024))[t] = pk;
}

// ---------------- W [1024][4096] fp32 -> Wt [4096][1024] bf16 ----------------
__global__ __launch_bounds__(256) void wt_cast_kernel(
    const float* __restrict__ W, unsigned short* __restrict__ Wt) {
    __shared__ float tile[32][33];
    const int bx = blockIdx.x;
    const int by = blockIdx.y;
    const int tx = threadIdx.x & 31;
    const int ty = threadIdx.x >> 5;
    #pragma unroll
    for (int i = 0; i < 4; ++i) {
        int k = by * 32 + ty + i * 8;
        tile[ty + i * 8][tx] = W[(size_t)k * 4096 + bx * 32 + tx];
    }
    __syncthreads();
    #pragma unroll
    for (int i = 0; i < 4; ++i) {
        int n = bx * 32 + ty + i * 8;
        Wt[(size_t)n * 1024 + by * 32 + tx] = f2bf(tile[tx][ty + i * 8]);
    }
}

// ---------------- GEMM 128x128 tile, BK=64, dbuf LDS 64KB, 2 blocks/CU ----------------
// R3 skeleton, reordered: ds_read(cur) -> stage(next) -> MFMA (compiler-counted
// lgkmcnt interleave, no explicit LDS drain) -> vmcnt(0) -> barrier.
__global__ __launch_bounds__(256, 2) void gemm_kernel(
    const unsigned short* __restrict__ A, const unsigned short* __restrict__ Wt,
    const float* __restrict__ bias, float* __restrict__ out) {
    __shared__ char lds_mem[65536];   // [2 bufs][A 16KB | B 16KB]

    const int bid = blockIdx.x;                 // 4096 blocks, %8==0 -> bijective
    const int swz = (bid & 7) * 512 + (bid >> 3);
    const int bm = swz >> 5;                    // 0..127
    const int bn = swz & 31;                    // 0..31

    const int t = threadIdx.x;
    const int lane = t & 63;
    const int wid = t >> 6;
    const int wm = wid >> 1, wn = wid & 1;
    const int lrow = lane & 15;
    const int lk = lane >> 4;                   // 0..3

    // staging: thread t -> row (t>>3)+32*i, 16B chunk (t&7); src pre-swizzled
    const int srr = t >> 3;                     // 0..31
    const int sch = t & 7;
    const int sgc = sch ^ (srr & 7);
    const unsigned short* gA = A  + (size_t)(bm * 128 + srr) * 1024 + sgc * 8;
    const unsigned short* gB = Wt + (size_t)(bn * 128 + srr) * 1024 + sgc * 8;
    const int lst = srr * 128 + sch * 16;

    auto stage = [&](int kt, char* buf) {
        #pragma unroll
        for (int i = 0; i < 4; ++i) {
            async_copy16(gA + (size_t)(i * 32) * 1024 + kt * 64, buf + i * 32 * 128 + lst);
            async_copy16(gB + (size_t)(i * 32) * 1024 + kt * 64, buf + 16384 + i * 32 * 128 + lst);
        }
    };

    // read-side swizzle: chunk c of frag-row r -> LDS 16B slot (c ^ (r&7)); r&7 == lrow&7
    const int ck0 = ((lk) ^ (lrow & 7)) * 16;
    const int ck1 = ((4 + lk) ^ (lrow & 7)) * 16;
    const int aBase = (wm * 64 + lrow) * 128;           // + mi*16*128
    const int bBase = 16384 + (wn * 64 + lrow) * 128;   // + ni*16*128

    f32x4 acc[4][4];
    #pragma unroll
    for (int i = 0; i < 4; ++i)
        #pragma unroll
        for (int j = 0; j < 4; ++j) acc[i][j] = (f32x4)0.0f;

    // bias hoisted above the K-loop
    float bv[4];
    #pragma unroll
    for (int ni = 0; ni < 4; ++ni) bv[ni] = bias[bn * 128 + wn * 64 + ni * 16 + lrow];

    // prologue
    stage(0, lds_mem);
    VM0();
    BARRIER();

    const int NKT = 16;
    for (int kt = 0; kt < NKT; ++kt) {
        char* cbuf = lds_mem + ((kt & 1) << 15);
        char* nbuf = lds_mem + (((kt + 1) & 1) << 15);

        // ds_reads FIRST (hit LDS port before staging writes queue up)
        bf16x8 af[4][2], bf[4][2];
        #pragma unroll
        for (int mi = 0; mi < 4; ++mi) {
            const char* p = cbuf + aBase + mi * 16 * 128;
            af[mi][0] = *(const bf16x8*)(p + ck0);
            af[mi][1] = *(const bf16x8*)(p + ck1);
        }
        #pragma unroll
        for (int ni = 0; ni < 4; ++ni) {
            const char* p = cbuf + bBase + ni * 16 * 128;
            bf[ni][0] = *(const bf16x8*)(p + ck0);
            bf[ni][1] = *(const bf16x8*)(p + ck1);
        }

        if (kt + 1 < NKT) stage(kt + 1, nbuf);   // issue next-tile loads

        // MFMA cluster — compiler inserts counted lgkmcnt as operands arrive
        __builtin_amdgcn_s_setprio(1);
        #pragma unroll
        for (int mi = 0; mi < 4; ++mi)
            #pragma unroll
            for (int ni = 0; ni < 4; ++ni) {
                acc[mi][ni] = __builtin_amdgcn_mfma_f32_16x16x32_bf16(af[mi][0], bf[ni][0], acc[mi][ni], 0, 0, 0);
                acc[mi][ni] = __builtin_amdgcn_mfma_f32_16x16x32_bf16(af[mi][1], bf[ni][1], acc[mi][ni], 0, 0, 0);
            }
        __builtin_amdgcn_s_setprio(0);

        if (kt + 1 < NKT) {
            VM0();       // next-tile gload_lds landed (hidden under reads+MFMA)
            BARRIER();   // all waves done with cbuf -> safe to restage next iter
        }
    }

    // ---- epilogue: bias + fast gelu, fp32 store
    #pragma unroll
    for (int mi = 0; mi < 4; ++mi) {
        const int row0 = bm * 128 + wm * 64 + mi * 16 + lk * 4;
        #pragma unroll
        for (int ni = 0; ni < 4; ++ni) {
            const int col = bn * 128 + wn * 64 + ni * 16 + lrow;
            #pragma unroll
            for (int r = 0; r < 4; ++r) {
                float y = acc[mi][ni][r] + bv[ni];
                out[(size_t)(row0 + r) * 4096 + col] = fast_gelu(y);
            }
        }
    }
}

extern "C" void kernel_launch(void* const* d_in, const int* in_sizes, int n_in,
                              void* d_out, int out_size, void* d_ws, size_t ws_size,
                              hipStream_t stream) {
    const float* hidden = (const float*)d_in[0];
    const float* gamma  = (const float*)d_in[1];
    const float* beta   = (const float*)d_in[2];
    const float* W      = (const float*)d_in[3];
    const float* bias   = (const float*)d_in[4];
    float* out = (float*)d_out;

    unsigned short* Abf = (unsigned short*)d_ws;
    unsigned short* Wt  = (unsigned short*)((char*)d_ws + (size_t)16384 * 1024 * 2);

    ln_cast_kernel<<<16384, 256, 0, stream>>>(hidden, gamma, beta, Abf);
    wt_cast_kernel<<<dim3(128, 32), 256, 0, stream>>>(W, Wt);
    gemm_kernel<<<4096, 256, 0, stream>>>(Abf, Wt, bias, out);
}